// Round 1
// baseline (223.725 us; speedup 1.0000x reference)
//
#include <hip/hip_runtime.h>
#include <stdint.h>

// out[p,b,o] = sum_i x*w0 + (1-x)*w1,  x,w in {0,1}
//            = sum_iw popc( (x & w0) | (~x & w1) )   -- one v_bfi_b32 + one
//              accumulating v_bcnt per word. Exact.
//
// R9: eliminate the xs[] LDS broadcast array (R8's co-bottleneck: 128
// ds_read_b128 broadcasts per wave per stage ~= 87us of LDS-pipe occupancy
// per CU, co-dominant with the 87us HBM w-stream). Each wave now keeps its
// own 32 rows x 16 words of packed x DISTRIBUTED in VGPRs (xw[8]/lane,
// refilled per stage from the L2-resident xp buffer) and broadcasts each
// word at use-site with v_readlane_b32 (compile-time lane index, feeds
// v_bfi_b32 as the SGPR operand). LDS now holds only the 16 KB double-
// buffered packed-w stage; one barrier per stage instead of two.
//   Block 1024 thr = (p, og-64), grid 512 -> 2 blocks/CU target (<=64 VGPR).
//   Per stage (16 iwords, 1/wave): prefetch next stage's w as 8-row dword
//   bursts, two rotating 8-reg slots, extraction deferred >= half-window;
//   x refill for stage s+1 issued after window 2 (xw[0..3] dead) and after
//   window 3 (xw[4..7] dead) so L2 latency hides under compute.
//   acc u16-packed pairs (out <= 2048, exact). Stage loop kept rolled
//   (#pragma unroll 1) to keep the body ~16 KB of I$.

#define NP 16
#define NB 512
#define NI 2048
#define NO 2048
#define JW 64               // u32 words per i-row
#define OG 64               // o-columns per block
#define NOG (NO / OG)       // 32
#define STW 16              // i-words per stage
#define NSTAGE (JW / STW)   // 4

__global__ __launch_bounds__(256) void pack_x_kernel(const float* __restrict__ x,
                                                     uint32_t* __restrict__ xp) {
    const int gtid = blockIdx.x * 256 + threadIdx.x;
    const int row  = gtid >> 6;     // p*NB + b
    const int lane = gtid & 63;
    const float* src = x + (size_t)row * NI;
    unsigned long long* dst = (unsigned long long*)(xp + (size_t)row * JW);
#pragma unroll 4
    for (int k = 0; k < NI / 64; ++k) {
        const float v = src[k * 64 + lane];
        const unsigned long long m = __ballot(v != 0.0f);
        if (lane == 0) dst[k] = m;
    }
}

// issue 8-row w burst b (0..3 = mat0 rows, 4..7 = mat1 rows) of i-word gi
#define WISSUE(dst, gi, b) do {                                                \
    const float* _s = wcol0 + ((b) < 4 ? (size_t)0 : (size_t)NP * wq)          \
                    + (size_t)((gi) * 32 + ((b) & 3) * 8) * NO;                \
    _Pragma("unroll")                                                          \
    for (int _u = 0; _u < 8; ++_u) dst[_u] = __float_as_uint(_s[(size_t)_u * NO]); \
} while (0)

// fold burst b's 8 loaded floats into bits (b&3)*8.. of nwd0/nwd1
#define WEXTRACT(src, b) do {                                                  \
    uint32_t _pt = 0;                                                          \
    _Pragma("unroll")                                                          \
    for (int _u = 0; _u < 8; ++_u) _pt |= ((src[_u] >> 23) & 1u) << _u;        \
    if ((b) < 4) nwd0 |= _pt << (((b) & 3) * 8);                               \
    else         nwd1 |= _pt << (((b) & 3) * 8);                               \
} while (0)

// refill this lane's distributed x words for stage s_ (lane l holds row
// wv*32 + (l>>1), words (l&1)*8 .. +7): word k of row r lives at
// lane = 2*(r - wv*32) + (k>>3), reg = k&7.
#define XLOAD_LO(s_) do {                                                      \
    *(uint4*)&xw[0] = *(const uint4*)(xbase + (s_) * STW);                     \
} while (0)
#define XLOAD_HI(s_) do {                                                      \
    *(uint4*)&xw[4] = *(const uint4*)(xbase + (s_) * STW + 4);                 \
} while (0)

// load the 4-iword w window for window `win` from wbuf[cur_]
#define WWIN(cur_, win) do {                                                   \
    _Pragma("unroll")                                                          \
    for (int _j = 0; _j < 4; ++_j) {                                           \
        const uint2 _p2 = *(const uint2*)&wbuf[cur_][(win) * 4 + _j][lane][0]; \
        w0r[_j] = _p2.x; w1r[_j] = _p2.y;                                      \
    }                                                                          \
} while (0)

// compute 8 row-pairs (half h) of window win; x via v_readlane broadcast
// from the wave's distributed xw regs (lane index is compile-time).
// word k = win*4+j -> reg (win&1)*4+j, lane-halfsel hi = win>>1.
#define HALFX(win, h) do {                                                     \
    _Pragma("unroll")                                                          \
    for (int _t = 0; _t < 8; ++_t) {                                           \
        const int _pr = (h) * 8 + _t;                                          \
        uint32_t _tA = 0, _tB = 0;                                             \
        _Pragma("unroll")                                                      \
        for (int _j = 0; _j < 4; ++_j) {                                       \
            const uint32_t _xa = (uint32_t)__builtin_amdgcn_readlane(          \
                (int)xw[((win) & 1) * 4 + _j], 4 * _pr + ((win) >> 1));        \
            const uint32_t _xb = (uint32_t)__builtin_amdgcn_readlane(          \
                (int)xw[((win) & 1) * 4 + _j], 4 * _pr + 2 + ((win) >> 1));    \
            _tA += __popc((_xa & w0r[_j]) | (~_xa & w1r[_j]));                 \
            _tB += __popc((_xb & w0r[_j]) | (~_xb & w1r[_j]));                 \
        }                                                                      \
        acc[_pr] += _tA + (_tB << 16);                                         \
    }                                                                          \
} while (0)

__global__ __launch_bounds__(1024) void evo_main(const float* __restrict__ w,
                                                 const uint32_t* __restrict__ xp,
                                                 float* __restrict__ out) {
    __shared__ uint32_t wbuf[2][STW][OG][2];   // 16 KB, double-buffered w bits

    const int tid  = threadIdx.x;
    const int lane = tid & 63;
    const int wv   = __builtin_amdgcn_readfirstlane(tid >> 6);  // 0..15
    const int p    = blockIdx.x >> 5;   // 0..15
    const int og   = blockIdx.x & 31;   // 0..31

    const size_t wq = (size_t)NI * NO;
    const float* wcol0 = w + (size_t)p * wq + (size_t)(og * OG + lane);
    const uint32_t* xbase = xp + ((size_t)p * NB + wv * 32 + (lane >> 1)) * JW
                          + (lane & 1) * 8;

    uint32_t acc[16];   // low16 = row 2t, high16 = row 2t+1 (<=2048, exact)
#pragma unroll
    for (int t = 0; t < 16; ++t) acc[t] = 0;

    uint32_t xw[8], va[8], vb[8], w0r[4], w1r[4];
    uint32_t nwd0 = 0, nwd1 = 0;

    // ---- prologue: x words (stage 0) + w i-word wv, 2-slot burst rotation ----
    XLOAD_LO(0); XLOAD_HI(0);
    {
        const int gi = wv;
        WISSUE(va, gi, 0); WISSUE(vb, gi, 1);
        WEXTRACT(va, 0);   WISSUE(va, gi, 2);
        WEXTRACT(vb, 1);   WISSUE(vb, gi, 3);
        WEXTRACT(va, 2);   WISSUE(va, gi, 4);
        WEXTRACT(vb, 3);   WISSUE(vb, gi, 5);
        wbuf[0][wv][lane][0] = nwd0;
        WEXTRACT(va, 4);   WISSUE(va, gi, 6);
        WEXTRACT(vb, 5);   WISSUE(vb, gi, 7);
        WEXTRACT(va, 6);
        WEXTRACT(vb, 7);
        wbuf[0][wv][lane][1] = nwd1;
    }
    __syncthreads();

    // ---- 4 stages; rolled loop (body ~16 KB of I$); last stage compute-only ----
#pragma unroll 1
    for (int s = 0; s < NSTAGE; ++s) {
        const int cur  = s & 1;
        const int more = (s + 1 < NSTAGE);
        const int gi1  = (s + 1) * STW + wv;
        if (more) { nwd0 = 0; nwd1 = 0;
                    WISSUE(va, gi1, 0); WISSUE(vb, gi1, 1); }
        WWIN(cur, 0); HALFX(0, 0);
        if (more) { WEXTRACT(va, 0); WISSUE(va, gi1, 2); }
        HALFX(0, 1);
        if (more) { WEXTRACT(vb, 1); WISSUE(vb, gi1, 3); }
        WWIN(cur, 1); HALFX(1, 0);
        if (more) { WEXTRACT(va, 2); WISSUE(va, gi1, 4); }
        HALFX(1, 1);
        if (more) { WEXTRACT(vb, 3); WISSUE(vb, gi1, 5);
                    wbuf[cur ^ 1][wv][lane][0] = nwd0; }
        WWIN(cur, 2); HALFX(2, 0);
        if (more) { WEXTRACT(va, 4); WISSUE(va, gi1, 6); }
        HALFX(2, 1);
        // xw[0..3] dead after window 2 -> refill overlaps window-3 compute
        if (more) { XLOAD_LO(s + 1); WEXTRACT(vb, 5); WISSUE(vb, gi1, 7); }
        WWIN(cur, 3); HALFX(3, 0);
        if (more) { WEXTRACT(va, 6); }
        HALFX(3, 1);
        if (more) { XLOAD_HI(s + 1); WEXTRACT(vb, 7);
                    wbuf[cur ^ 1][wv][lane][1] = nwd1; }
        __syncthreads();
    }

    // ---- epilogue: unpack u16 pairs, coalesced stores ----
    float* obase = out + ((size_t)p * NB + wv * 32) * NO + (size_t)og * OG + lane;
#pragma unroll
    for (int t = 0; t < 16; ++t) {
        obase[(size_t)(2 * t) * NO]     = (float)(acc[t] & 0xFFFFu);
        obase[(size_t)(2 * t + 1) * NO] = (float)(acc[t] >> 16);
    }
}

extern "C" void kernel_launch(void* const* d_in, const int* in_sizes, int n_in,
                              void* d_out, int out_size, void* d_ws, size_t ws_size,
                              hipStream_t stream) {
    const float* x = (const float*)d_in[0];   // (16,512,2048) fp32 {0,1}
    const float* w = (const float*)d_in[1];   // (2,16,1,2048,2048) fp32 {0,1}
    float* out     = (float*)d_out;           // (16,512,2048) fp32
    uint32_t* xp   = (uint32_t*)d_ws;         // 2 MB packed x

    pack_x_kernel<<<dim3((NP * NB * 64) / 256), dim3(256), 0, stream>>>(x, xp);
    evo_main<<<dim3(NP * NOG), dim3(1024), 0, stream>>>(w, xp, out);
}